// Round 8
// baseline (475.912 us; speedup 1.0000x reference)
//
#include <hip/hip_runtime.h>
#include <hip/hip_bf16.h>
#include <cstdint>
#include <cstddef>

// Problem dims (fixed by reference)
#define B_DIM 4
#define T_DIM 4096
#define D_DIM 2048
#define M_DIM 512
#define NTOK  (B_DIM * T_DIM)     // 16384 rows
#define KCOMB (D_DIM + M_DIM)     // 2560
#define NCHUNK 64                 // chunks per chain for the parallel scan
#define CLEN   64                 // T / NCHUNK

typedef __attribute__((ext_vector_type(8)))  __bf16 bf16x8;  // MFMA A/B frag (4 VGPRs)
typedef __attribute__((ext_vector_type(16))) float  f32x16;  // 32x32 MFMA C/D frag
typedef __attribute__((ext_vector_type(4)))  float  f32x4;   // 16x16 MFMA C/D frag

__device__ __forceinline__ unsigned short f2bf(float f) {
  union { float f; unsigned u; } v; v.f = f;
  unsigned r = v.u + 0x7fffu + ((v.u >> 16) & 1u);  // RNE
  return (unsigned short)(r >> 16);
}

__device__ __forceinline__ float bf2f(unsigned short u) {
  union { unsigned u; float f; } v; v.u = ((unsigned)u) << 16;
  return v.f;
}

__device__ __forceinline__ float sigmoidf(float x) { return 1.0f / (1.0f + expf(-x)); }

// ---- fused casts: x -> comb[:, :D] (stride KCOMB), Wv -> WvB, Wg -> WgB ----
#define XBLK  ((NTOK * D_DIM / 4) / 256)            // 32768
#define WVBLK ((M_DIM * D_DIM / 4) / 256)           // 1024
#define WGBLK ((D_DIM * KCOMB / 4) / 256)           // 5120
__global__ void cast_all_kernel(const float* __restrict__ x, const float* __restrict__ Wv,
                                const float* __restrict__ Wg,
                                unsigned short* __restrict__ comb,
                                unsigned short* __restrict__ WvB,
                                unsigned short* __restrict__ WgB) {
  int bid = blockIdx.x;
  const float* src; unsigned short* dst; size_t soff, doff;
  if (bid < XBLK) {
    int idx = bid * 256 + threadIdx.x;
    int n = idx >> 9;                               // D/4 = 512 quads per row
    int c = (idx & 511) << 2;
    src = x;   soff = (size_t)n * D_DIM + c;
    dst = comb; doff = (size_t)n * KCOMB + c;
  } else if (bid < XBLK + WVBLK) {
    int idx = (bid - XBLK) * 256 + threadIdx.x;
    src = Wv;  soff = (size_t)idx * 4;
    dst = WvB; doff = (size_t)idx * 4;
  } else {
    int idx = (bid - XBLK - WVBLK) * 256 + threadIdx.x;
    src = Wg;  soff = (size_t)idx * 4;
    dst = WgB; doff = (size_t)idx * 4;
  }
  float4 v = *(const float4*)(src + soff);
  ushort4 o;
  o.x = f2bf(v.x); o.y = f2bf(v.y); o.z = f2bf(v.z); o.w = f2bf(v.w);
  *(ushort4*)(dst + doff) = o;
}

// ---- scan phase 1: per-chunk affine partial  P[b][c][m] = sum_i decay^{CLEN-1-i} v[...] ----
__global__ __launch_bounds__(M_DIM) void recur_partial(
    const float* __restrict__ v, const float* __restrict__ td, float* __restrict__ P) {
  int m = threadIdx.x;
  int b = blockIdx.x >> 6;
  int c = blockIdx.x & (NCHUNK - 1);
  float decay = sigmoidf(td[m]) * 0.9f + 0.1f;
  const float* vp = v + ((size_t)(b * T_DIM + c * CLEN)) * M_DIM + m;
  float p = 0.0f;
  for (int t0 = 0; t0 < CLEN; t0 += 8) {
    float vt[8];
#pragma unroll
    for (int u = 0; u < 8; ++u) vt[u] = vp[(size_t)(t0 + u) * M_DIM];
#pragma unroll
    for (int u = 0; u < 8; ++u) p = p * decay + vt[u];
  }
  P[(size_t)blockIdx.x * M_DIM + m] = p;
}

// ---- scan phases 2+3: fold prefix partials -> chunk start state, then replay chunk ----
__global__ __launch_bounds__(M_DIM) void recur_apply(
    const float* __restrict__ v, const float* __restrict__ mem0,
    const float* __restrict__ td, const float* __restrict__ tf,
    const float* __restrict__ P,
    unsigned short* __restrict__ comb, float* __restrict__ nmem) {
  int m = threadIdx.x;
  int b = blockIdx.x >> 6;
  int c = blockIdx.x & (NCHUNK - 1);
  float decay = sigmoidf(td[m]) * 0.9f + 0.1f;
  float first = sigmoidf(tf[m]);
  float dL = decay;  // decay^64 via 6 squarings
  dL = dL * dL; dL = dL * dL; dL = dL * dL; dL = dL * dL; dL = dL * dL; dL = dL * dL;

  float s = mem0[b * M_DIM + m];
  const float* Pp = P + (size_t)(b * NCHUNK) * M_DIM + m;
  for (int ci = 0; ci < c; ++ci)
    s = s * dL + Pp[(size_t)ci * M_DIM];

  const float* vp = v + ((size_t)(b * T_DIM + c * CLEN)) * M_DIM + m;
  unsigned short* wp = comb + ((size_t)(b * T_DIM + c * CLEN)) * KCOMB + D_DIM + m;
  for (int t0 = 0; t0 < CLEN; t0 += 8) {
    float vt[8];
#pragma unroll
    for (int u = 0; u < 8; ++u) vt[u] = vp[(size_t)(t0 + u) * M_DIM];
#pragma unroll
    for (int u = 0; u < 8; ++u) {
      wp[(size_t)(t0 + u) * KCOMB] = f2bf(vt[u] + s * first);
      s = s * decay + vt[u];
    }
  }
  if (c == NCHUNK - 1) nmem[b * M_DIM + m] = s;
}

// ---- GEMM1: bf16 GEMM, C[row,col] = sum_k A[row,k]*B[col,k] (+bias[col]) ----
// 128x128 tile, BK=64, 32x32x16 MFMA, 2-phase loop. Kept for the NTOK x 512
// shape; ~5 blocks/CU gives cross-wave overlap (m97 regime).
#define BM 128
#define BN 128
#define BK 64

template <bool ADD_X, int MODE>
__global__ __launch_bounds__(256) void gemm_bt(
    const unsigned short* __restrict__ A, int lda,
    const unsigned short* __restrict__ B, int ldb,
    const float* __restrict__ bias, const float* __restrict__ xadd,
    float* __restrict__ C, int N, int K) {
  const int tid = threadIdx.x;
  const int lane = tid & 63;
  const int wave = tid >> 6;
  const int wm = (wave >> 1) * 64;   // wave row offset in tile
  const int wn = (wave & 1) * 64;    // wave col offset in tile
  const int l31 = lane & 31;
  const int half = lane >> 5;

  int tileM, tileN;
  {
    int idx = blockIdx.x;
    int xcd = idx & 7, local = idx >> 3;
    if (MODE == 1) {
      tileN = (xcd * 2 + (local & 1)) * BN;
      tileM = (local >> 1) * BM;
    } else {                    // GEMM1: 128x4 tiles
      tileM = (xcd * 16 + (local >> 2)) * BM;
      tileN = (local & 3) * BN;
    }
  }

  __shared__ unsigned short As[BM * BK];  // 16 KiB
  __shared__ unsigned short Bs[BN * BK];  // 16 KiB

  f32x16 acc[2][2] = {};

  for (int k0 = 0; k0 < K; k0 += BK) {
#pragma unroll
    for (int j = 0; j < 4; ++j) {
      int c = j * 256 + tid;
      int row = c >> 3;
      int kc = c & 7;
      int gkc = kc ^ (row & 7);
      const unsigned short* gA = A + (size_t)(tileM + row) * lda + k0 + gkc * 8;
      const unsigned short* gB = B + (size_t)(tileN + row) * ldb + k0 + gkc * 8;
      __builtin_amdgcn_global_load_lds((const __attribute__((address_space(1))) void*)gA,
                                       (__attribute__((address_space(3))) void*)(As + c * 8),
                                       16, 0, 0);
      __builtin_amdgcn_global_load_lds((const __attribute__((address_space(1))) void*)gB,
                                       (__attribute__((address_space(3))) void*)(Bs + c * 8),
                                       16, 0, 0);
    }
    __syncthreads();

#pragma unroll
    for (int s = 0; s < 4; ++s) {
      const int g = s * 2 + half;
      bf16x8 af[2], bfr[2];
#pragma unroll
      for (int i = 0; i < 2; ++i) {
        int ra = wm + i * 32 + l31;
        int rb = wn + i * 32 + l31;
        af[i]  = *(const bf16x8*)(As + ra * BK + ((g ^ (ra & 7)) * 8));
        bfr[i] = *(const bf16x8*)(Bs + rb * BK + ((g ^ (rb & 7)) * 8));
      }
#pragma unroll
      for (int mi = 0; mi < 2; ++mi)
#pragma unroll
        for (int ni = 0; ni < 2; ++ni)
          acc[mi][ni] = __builtin_amdgcn_mfma_f32_32x32x16_bf16(af[mi], bfr[ni], acc[mi][ni], 0, 0, 0);
    }
    __syncthreads();
  }

#pragma unroll
  for (int mi = 0; mi < 2; ++mi) {
#pragma unroll
    for (int ni = 0; ni < 2; ++ni) {
      int col = tileN + wn + ni * 32 + l31;
      float bcol = bias[col];
#pragma unroll
      for (int r = 0; r < 16; ++r) {
        int row = tileM + wm + mi * 32 + 4 * half + (r & 3) + 8 * (r >> 2);
        float val = acc[mi][ni][r] + bcol;
        if (ADD_X) val += xadd[(size_t)row * N + col];
        C[(size_t)row * N + col] = val;
      }
    }
  }
}

// ---- GEMM2: 256x256 pipelined bf16 GEMM, v7 (WAR-free register schedule) ----
// r7 theory: v6's wall = LDS(5.6k) + MFMA(5.0k) cyc/CU-iter IN SUM — the pipes
// never overlap because every quadrant reloads the SAME af[] registers, so
// quadrant q+1's ds_reads WAR-depend on quadrant q's MFMAs. v7 doubles the
// A-frag set (afA=mh0, afB=mh1) and issues ALL 24 window reads up-front with
// no register reuse; the first MFMA quadrant starts after its 12 operands
// land while the other 12 reads drain UNDER 48 in-flight MFMAs. +32 VGPR is
// free (occupancy is LDS-capped at 1 block = 8 waves/CU, not VGPR-capped).
//
// Barrier/stage/vmcnt schedule identical to v6 (4 barriers/iter):
//   W0: stage B(b1)<-t+1; 24 reads buf0; M(0,0)(0,1)(1,1);
//   BAR_A [all buf0 reads consumed pre-barrier]; stage A(b0),B(b0)<-t+2;
//   M(1,0) (register-only); vmcnt(8) [drains buf1]; BAR_B;
//   W1: same on buf1; BAR_C; stage A(b1)<-t+3; M(1,0); vmcnt(4); BAR_D.
#define BAR_FENCE() do { asm volatile("" ::: "memory"); \
  __builtin_amdgcn_s_barrier(); asm volatile("" ::: "memory"); } while (0)

template <bool ADD_X, int LDA, int LDB, int NOUT, int KTOT>
__global__ __launch_bounds__(512, 2) void gemm256_bt(
    const unsigned short* __restrict__ Amat,
    const unsigned short* __restrict__ Bmat,
    const float* __restrict__ bias,
    const unsigned short* __restrict__ xadd,   // bf16, row stride LDA (comb)
    float* __restrict__ C) {
  constexpr int NK  = KTOT / 64;          // 40 K-tiles
  constexpr int NI  = NK / 2;             // 20 iterations (2 tiles each)
  constexpr int NTN = NOUT / 256;         // 8 tile-cols
  constexpr int NWG = (NTOK / 256) * NTN; // 512 workgroups
  constexpr int PERX = NWG / 8;           // 64 per XCD

  __shared__ unsigned short As[2][256 * 64];  // 64 KiB
  __shared__ unsigned short Bs[2][256 * 64];  // 64 KiB

  const int tid  = threadIdx.x;
  const int lane = tid & 63;
  const int l15  = lane & 15;
  const int g4   = lane >> 4;           // 16x16x32 k-group (0..3)
  const int wave = tid >> 6;
  const int wrow = (wave >> 2) * 128;   // 2 wave-rows
  const int wcol = (wave & 3) * 64;     // 4 wave-cols

  // XCD-aware swizzle (512 % 8 == 0 -> bijective).
  const int bid   = blockIdx.x;
  const int wgid  = (bid & 7) * PERX + (bid >> 3);
  const int tileM = (wgid / NTN) * 256;
  const int tileN = (wgid % NTN) * 256;

  // Per-thread staging source (global-side XOR pre-swizzle; row&7 invariant
  // under +64/+128 row offsets, so one base pointer serves all half-tiles).
  const int row_lo = tid >> 3;                              // 0..63
  const int scol   = (((tid & 7) ^ (row_lo & 7)) << 3);
  const unsigned short* pA = Amat + (size_t)(tileM + row_lo) * LDA + scol;
  const unsigned short* pB = Bmat + (size_t)(tileN + row_lo) * LDB + scol;

#define GSTAGE_A(b, h, kt) do { \
  _Pragma("unroll") for (int j = 0; j < 2; ++j) { \
    const unsigned short* _s = pA + (size_t)((h) * 128 + j * 64) * LDA + (kt) * 64; \
    __builtin_amdgcn_global_load_lds((const __attribute__((address_space(1))) void*)_s, \
        (__attribute__((address_space(3))) void*)(&As[(b)][(h) * 8192 + (j * 512 + tid) * 8]), \
        16, 0, 0); \
  } \
} while (0)

#define GSTAGE_B(b, h, kt) do { \
  _Pragma("unroll") for (int j = 0; j < 2; ++j) { \
    const unsigned short* _s = pB + (size_t)((h) * 128 + j * 64) * LDB + (kt) * 64; \
    __builtin_amdgcn_global_load_lds((const __attribute__((address_space(1))) void*)_s, \
        (__attribute__((address_space(3))) void*)(&Bs[(b)][(h) * 8192 + (j * 512 + tid) * 8]), \
        16, 0, 0); \
  } \
} while (0)

  f32x4  acc[8][4] = {};   // 128 regs (AGPR side of unified file)
  bf16x8 afA[4][2];        // A mh=0 set: 4 m-tiles x 2 ksteps (32 VGPR)
  bf16x8 afB[4][2];        // A mh=1 set (32 VGPR) — kills the quadrant WAR chain
  bf16x8 bf[2][2];         // B nh=0 set (16 VGPR)
  bf16x8 bg[2][2];         // B nh=1 set (16 VGPR)

  // 16x16x32 fragment: lane holds row (l&15), k = (l>>4)*8.. within kstep*32.
  // LDS chunk c of row r holds global chunk c^(r&7) -> read chunk q^(r&7).
#define GREAD_A(b, mh, dst) do { \
  _Pragma("unroll") for (int mt = 0; mt < 4; ++mt) { \
    const int _r = wrow + (mh) * 64 + mt * 16 + l15; \
    _Pragma("unroll") for (int ks = 0; ks < 2; ++ks) \
      dst[mt][ks] = *(const bf16x8*)(&As[(b)][_r * 64 + (((ks * 4 + g4) ^ (_r & 7)) << 3)]); \
  } \
} while (0)

#define GREAD_B(b, nh, dst) do { \
  _Pragma("unroll") for (int nt = 0; nt < 2; ++nt) { \
    const int _r = wcol + (nh) * 32 + nt * 16 + l15; \
    _Pragma("unroll") for (int ks = 0; ks < 2; ++ks) \
      dst[nt][ks] = *(const bf16x8*)(&Bs[(b)][_r * 64 + (((ks * 4 + g4) ^ (_r & 7)) << 3)]); \
  } \
} while (0)

// 16 MFMA: 8 independent (mt,nt) chains x depth 2 (ks)
#define GMFMA_Q(mh, nh, areg, breg) do { \
  __builtin_amdgcn_s_setprio(1); \
  _Pragma("unroll") for (int ks = 0; ks < 2; ++ks) \
    _Pragma("unroll") for (int mt = 0; mt < 4; ++mt) \
      _Pragma("unroll") for (int nt = 0; nt < 2; ++nt) \
        acc[(mh) * 4 + mt][(nh) * 2 + nt] = __builtin_amdgcn_mfma_f32_16x16x32_bf16( \
            areg[mt][ks], breg[nt][ks], acc[(mh) * 4 + mt][(nh) * 2 + nt], 0, 0, 0); \
  __builtin_amdgcn_s_setprio(0); \
} while (0)

  // Prologue: buf0 <- tile0 (8 loads, oldest), buf1 <- A of tile1 (4 loads).
  // vmcnt(4): buf0 resident; buf1's A stays in flight (B(b1) staged in W0).
  GSTAGE_A(0, 0, 0); GSTAGE_A(0, 1, 0);
  GSTAGE_B(0, 0, 0); GSTAGE_B(0, 1, 0);
  GSTAGE_A(1, 0, 1); GSTAGE_A(1, 1, 1);
  asm volatile("s_waitcnt vmcnt(4)" ::: "memory");
  BAR_FENCE();

#define GITER(i2, FULL) do { \
  /* ---- window W0: buf0 = tile i2; stage B(b1)<-i2+1 ---- */ \
  GSTAGE_B(1, 0, (i2) + 1); GSTAGE_B(1, 1, (i2) + 1); \
  GREAD_A(0, 0, afA); GREAD_B(0, 0, bf); \
  GREAD_B(0, 1, bg);  GREAD_A(0, 1, afB); \
  GMFMA_Q(0, 0, afA, bf); \
  GMFMA_Q(0, 1, afA, bg); \
  GMFMA_Q(1, 1, afB, bg); \
  BAR_FENCE();  /* BAR_A: all 24 buf0 reads consumed by MFMAs above */ \
  if (FULL) { GSTAGE_A(0, 0, (i2) + 2); GSTAGE_A(0, 1, (i2) + 2); \
              GSTAGE_B(0, 0, (i2) + 2); GSTAGE_B(0, 1, (i2) + 2); } \
  GMFMA_Q(1, 0, afB, bf);  /* register-only, overlaps stage issue + drain */ \
  if (FULL) asm volatile("s_waitcnt vmcnt(8)" ::: "memory"); \
  else      asm volatile("s_waitcnt vmcnt(0)" ::: "memory"); \
  BAR_FENCE();  /* BAR_B: buf1 = tile i2+1 ready */ \
  /* ---- window W1: buf1 = tile i2+1 ---- */ \
  GREAD_A(1, 0, afA); GREAD_B(1, 0, bf); \
  GREAD_B(1, 1, bg);  GREAD_A(1, 1, afB); \
  GMFMA_Q(0, 0, afA, bf); \
  GMFMA_Q(0, 1, afA, bg); \
  GMFMA_Q(1, 1, afB, bg); \
  BAR_FENCE();  /* BAR_C: buf1 reads all consumed */ \
  if (FULL) { GSTAGE_A(1, 0, (i2) + 3); GSTAGE_A(1, 1, (i2) + 3); } \
  GMFMA_Q(1, 0, afB, bf); \
  if (FULL) { asm volatile("s_waitcnt vmcnt(4)" ::: "memory"); \
              BAR_FENCE(); }  /* BAR_D: buf0 = tile i2+2 ready */ \
} while (0)

#pragma unroll 1
  for (int i = 0; i < NI - 1; ++i) GITER(2 * i, 1);
  GITER(2 * (NI - 1), 0);   // last iter: vmcnt(0) at the W0 gate; no trailing gate

#undef GITER
#undef GMFMA_Q
#undef GREAD_B
#undef GREAD_A
#undef GSTAGE_B
#undef GSTAGE_A

  // Epilogue: 16x16 C/D layout col=lane&15, row=(lane>>4)*4+reg (m89/m91).
  // x-add reads bf16 x from comb (col < D region) — saves the fp32 x re-read.
#pragma unroll
  for (int mt = 0; mt < 8; ++mt) {
#pragma unroll
    for (int nt = 0; nt < 4; ++nt) {
      const int col = tileN + wcol + nt * 16 + l15;
      const float bc = bias[col];
#pragma unroll
      for (int r = 0; r < 4; ++r) {
        const int row = tileM + wrow + mt * 16 + g4 * 4 + r;
        float val = acc[mt][nt][r] + bc;
        if (ADD_X) val += bf2f(xadd[(size_t)row * LDA + col]);
        C[(size_t)row * NOUT + col] = val;
      }
    }
  }
}

extern "C" void kernel_launch(void* const* d_in, const int* in_sizes, int n_in,
                              void* d_out, int out_size, void* d_ws, size_t ws_size,
                              hipStream_t stream) {
  const float* x   = (const float*)d_in[0];
  const float* mem = (const float*)d_in[1];
  const float* Wv  = (const float*)d_in[2];
  const float* bv  = (const float*)d_in[3];
  const float* Wg  = (const float*)d_in[4];
  const float* bg  = (const float*)d_in[5];
  const float* td  = (const float*)d_in[6];
  const float* tf  = (const float*)d_in[7];
  float* out = (float*)d_out;  // [NTOK, D] output, then [B*M] next_memory

  // Workspace layout
  char* ws = (char*)d_ws;
  unsigned short* comb = (unsigned short*)ws;                              // [NTOK, KCOMB] bf16
  float* v = (float*)(ws + (size_t)NTOK * KCOMB * 2);                      // [NTOK, M] fp32
  unsigned short* WvB = (unsigned short*)((char*)v + (size_t)NTOK * M_DIM * 4);   // [M, D] bf16
  unsigned short* WgB = (unsigned short*)((char*)WvB + (size_t)M_DIM * D_DIM * 2); // [D, KCOMB] bf16
  float* P = (float*)WvB;  // aliases WvB (dead after GEMM1); P is 512 KB

  // 1. fused casts
  cast_all_kernel<<<XBLK + WVBLK + WGBLK, 256, 0, stream>>>(x, Wv, Wg, comb, WvB, WgB);

  // 2. v = x_bf16 . Wv^T + bv   (A = combined[:, :D] via lda=KCOMB)
  gemm_bt<false, 0><<<(NTOK / BM) * (M_DIM / BN), 256, 0, stream>>>(
      comb, KCOMB, WvB, D_DIM, bv, nullptr, v, M_DIM, D_DIM);

  // 3. parallel scan: chunk partials, then prefix-fold + replay
  recur_partial<<<B_DIM * NCHUNK, M_DIM, 0, stream>>>(v, td, P);
  recur_apply<<<B_DIM * NCHUNK, M_DIM, 0, stream>>>(
      v, mem, td, tf, P, comb, out + (size_t)NTOK * D_DIM);

  // 4. out = x + combined . Wg^T + bg   (256^2 4-barrier kernel, v7 WAR-free)
  gemm256_bt<true, KCOMB, KCOMB, D_DIM, KCOMB>
      <<<(NTOK / 256) * (D_DIM / 256), 512, 0, stream>>>(comb, WgB, bg, comb, out);
}